// Round 7
// baseline (1658.952 us; speedup 1.0000x reference)
//
#include <hip/hip_runtime.h>
#include <math.h>

// HydraScaleLM forward. Round 7: scanf XCD-chunked swizzle (adjacent-d blocks
// share an L2 -> kills 4x read / 8x write amplification), uu[] dropped
// (recompute conv in phase C, VGPR 112->~80), per-layer weight cvts fused into
// one dispatch. GEMM structure unchanged from round 6.
// Shapes: B=2, S=512, D=1024, DEPTH=4, N=16, K=4, R=64, MLP=4096, V=32000. M=1024.

#define DEV __device__ __forceinline__
typedef unsigned int u32;
typedef unsigned short ushort;
typedef __bf16 bf16x8 __attribute__((ext_vector_type(8)));
typedef float f32x4 __attribute__((ext_vector_type(4)));
typedef ushort us8 __attribute__((ext_vector_type(8)));

DEV float silu_f(float x){ return x / (1.f + expf(-x)); }
DEV float gelu_f(float x){ return 0.5f * x * (1.f + erff(x * 0.70710678118654752f)); }
DEV float softplus_f(float x){ return (x > 20.f) ? x : log1pf(expf(x)); }
DEV ushort f2b(float f){
  u32 u = __builtin_bit_cast(u32, f);
  return (ushort)((u + 0x7fffu + ((u >> 16) & 1u)) >> 16);
}

DEV void gl_lds16(const ushort* g, ushort* l){
  __builtin_amdgcn_global_load_lds(
      (const __attribute__((address_space(1))) u32*)g,
      (__attribute__((address_space(3))) u32*)l, 16, 0, 0);
}

// ---------------- fused per-layer weight conversion ----------------
// segments (float4 units): z 262144 | p-pad 32768 | dt 16384 | o 262144 |
//                          m1 1048576 | m2 1048576   (total 2670656)
__global__ __launch_bounds__(256) void k_cvtall(
    const float* __restrict__ zWl, const float* __restrict__ pWl,
    const float* __restrict__ dtWl, const float* __restrict__ oWl,
    const float* __restrict__ m1Wl, const float* __restrict__ m2Wl,
    ushort* __restrict__ wzb, ushort* __restrict__ wpb,
    ushort* __restrict__ wdtb, ushort* __restrict__ wob,
    ushort* __restrict__ wm1b, ushort* __restrict__ wm2b)
{
  int i = blockIdx.x*256 + threadIdx.x;
  const float* src; ushort* dst; int j;
  if (i < 262144){ src = zWl; dst = wzb; j = i; }
  else if (i < 262144+32768){
    j = i - 262144; dst = wpb;
    int row = j >> 8;                      // (j*4)>>10
    if (row >= 96){ ushort4 o0={0,0,0,0}; ((ushort4*)dst)[j] = o0; return; }
    src = pWl;
  }
  else if (i < 262144+32768+16384){ j = i - (262144+32768); src = dtWl; dst = wdtb; }
  else if (i < 573440)            { j = i - (262144+32768+16384); src = oWl; dst = wob; }
  else if (i < 573440+1048576)    { j = i - 573440; src = m1Wl; dst = wm1b; }
  else if (i < 2670656)           { j = i - (573440+1048576); src = m2Wl; dst = wm2b; }
  else return;
  float4 v = ((const float4*)src)[j];
  ushort4 o; o.x=f2b(v.x); o.y=f2b(v.y); o.z=f2b(v.z); o.w=f2b(v.w);
  ((ushort4*)dst)[j] = o;
}

__global__ __launch_bounds__(256) void k_cvt(const float* __restrict__ in, ushort* __restrict__ out, int n4){
  int i = blockIdx.x*256 + threadIdx.x;
  if (i >= n4) return;
  float4 v = ((const float4*)in)[i];
  ushort4 o; o.x=f2b(v.x); o.y=f2b(v.y); o.z=f2b(v.z); o.w=f2b(v.w);
  ((ushort4*)out)[i] = o;
}

// p[1024][96] fp32 -> pb[1024][64] bf16 (dt_un slice)
__global__ __launch_bounds__(256) void k_cvtp(const float* __restrict__ p, ushort* __restrict__ pb){
  int i = blockIdx.x*256 + threadIdx.x;      // 16384 float4s
  int row = i >> 4, c4 = i & 15;
  float4 v = *(const float4*)(p + row*96 + c4*4);
  ushort4 o; o.x=f2b(v.x); o.y=f2b(v.y); o.z=f2b(v.z); o.w=f2b(v.w);
  *(ushort4*)(pb + row*64 + c4*4) = o;
}

// ---------------- time embedding ----------------
__global__ __launch_bounds__(256) void k_temb0(const int* __restrict__ ts, float* __restrict__ temb0){
  int t = blockIdx.x*256 + threadIdx.x;
  if (t >= 2*512) return;
  int b = t >> 9, i = t & 511;
  float tv = (float)ts[b];
  float inv = expf(-(9.210340371976184f/512.f) * (float)i);
  float a = tv * inv;
  temb0[b*1024 + i]       = sinf(a);
  temb0[b*1024 + 512 + i] = cosf(a);
}

__global__ __launch_bounds__(256) void k_temb1(const float* __restrict__ t0, const float* __restrict__ w1,
                                               const float* __restrict__ b1, float* __restrict__ t1){
  int o = blockIdx.x*4 + (threadIdx.x >> 6);
  int lane = threadIdx.x & 63;
  int b = o >> 12, j = o & 4095;
  const float4* xr = (const float4*)(t0 + b*1024);
  const float4* wr = (const float4*)(w1 + (size_t)j*1024);
  float acc = 0.f;
  #pragma unroll
  for (int i=0;i<4;i++){
    float4 x4 = xr[i*64 + lane], w4 = wr[i*64 + lane];
    acc += x4.x*w4.x + x4.y*w4.y + x4.z*w4.z + x4.w*w4.w;
  }
  #pragma unroll
  for (int off=32; off; off>>=1) acc += __shfl_down(acc, off);
  if (lane==0) t1[o] = silu_f(acc + b1[j]);
}

__global__ __launch_bounds__(256) void k_temb2(const float* __restrict__ t1, const float* __restrict__ w2,
                                               const float* __restrict__ b2, float* __restrict__ t2){
  int o = blockIdx.x*4 + (threadIdx.x >> 6);
  int lane = threadIdx.x & 63;
  int b = o >> 10, j = o & 1023;
  const float4* xr = (const float4*)(t1 + b*4096);
  const float4* wr = (const float4*)(w2 + (size_t)j*4096);
  float acc = 0.f;
  #pragma unroll
  for (int i=0;i<16;i++){
    float4 x4 = xr[i*64 + lane], w4 = wr[i*64 + lane];
    acc += x4.x*w4.x + x4.y*w4.y + x4.z*w4.z + x4.w*w4.w;
  }
  #pragma unroll
  for (int off=32; off; off>>=1) acc += __shfl_down(acc, off);
  if (lane==0) t2[o] = acc + b2[j];
}

// ---------------- embed ----------------
__global__ __launch_bounds__(256) void k_embed(const int* __restrict__ ids, const float* __restrict__ tok,
                                               const float* __restrict__ t2, float* __restrict__ x){
  int i = blockIdx.x*256 + threadIdx.x;
  int bs = i >> 10, d = i & 1023;
  int id = ids[bs];
  x[i] = tok[(size_t)id*1024 + d] + t2[((bs >> 9) << 10) + d];
}

// ---------------- layernorm: writes fp32 + bf16 ----------------
__global__ __launch_bounds__(256) void k_ln(const float* __restrict__ x, const float* __restrict__ sc,
                                            const float* __restrict__ bi, float* __restrict__ o,
                                            ushort* __restrict__ obf){
  int row = blockIdx.x;
  int t = threadIdx.x;
  float4 v = ((const float4*)(x + (size_t)row*1024))[t];
  float sum = v.x+v.y+v.z+v.w;
  float sq  = v.x*v.x+v.y*v.y+v.z*v.z+v.w*v.w;
  for (int o_=32;o_;o_>>=1){ sum += __shfl_down(sum,o_); sq += __shfl_down(sq,o_); }
  __shared__ float ps[8];
  int lane = t & 63, wid = t >> 6;
  if (lane==0){ ps[wid]=sum; ps[4+wid]=sq; }
  __syncthreads();
  float tot = ps[0]+ps[1]+ps[2]+ps[3];
  float tsq = ps[4]+ps[5]+ps[6]+ps[7];
  float m = tot * (1.f/1024.f);
  float var = tsq*(1.f/1024.f) - m*m;
  float r = rsqrtf(var + 1e-5f);
  float4 s4 = ((const float4*)sc)[t];
  float4 b4 = ((const float4*)bi)[t];
  float4 o4;
  o4.x = (v.x-m)*r*s4.x + b4.x;
  o4.y = (v.y-m)*r*s4.y + b4.y;
  o4.z = (v.z-m)*r*s4.z + b4.z;
  o4.w = (v.w-m)*r*s4.w + b4.w;
  ((float4*)(o + (size_t)row*1024))[t] = o4;
  ushort4 ob; ob.x=f2b(o4.x); ob.y=f2b(o4.y); ob.z=f2b(o4.z); ob.w=f2b(o4.w);
  ((ushort4*)(obf + (size_t)row*1024))[t] = ob;
}

// ---------------- fused conv + chunk-parallel SSM scan + ypost ----------------
// XCD-chunked swizzle: blocks with adjacent d land on the SAME XCD so the
// 16 d-sharers of each 64B line of dt/xn/z/y2b hit one L2 (read reuse +
// write combining). VGPR trimmed: uu[] recomputed in phase C.
__global__ __launch_bounds__(256) void k_scanf(
    const float* __restrict__ dt, const float* __restrict__ xn,
    const float* __restrict__ p,  const float* __restrict__ alog,
    const float* __restrict__ z,  const float* __restrict__ Dp,
    const float* __restrict__ cw, ushort* __restrict__ y2b)
{
  const int bid = blockIdx.x;                      // 2048
  const int logical = (bid & 7)*256 + (bid >> 3);  // XCD k owns logical k*256..+255
  const int d = logical & 1023;
  const int b = logical >> 10;
  const int tid = threadIdx.x;
  const int c = tid >> 4, n = tid & 15;
  const float al = alog[d*16 + n];
  const float A = -expf(al);
  const float invA = 1.f/(A + 1e-10f);
  const bool tiny = fabsf(A) < 1e-8f;
  const float dscale = Dp[d];
  const float cw0 = cw[d*4], cw1 = cw[d*4+1], cw2 = cw[d*4+2], cw3 = cw[d*4+3];
  const size_t base = (size_t)b*512*1024 + d;
  const float* pp = p + (size_t)b*512*96;
  const int s0 = c*32;

  __shared__ float sA[256], sB[256], sH[256];

  float At[32], inp[32];
  float xw0 = (s0>=3) ? xn[base + (size_t)(s0-3)*1024] : 0.f;
  float xw1 = (s0>=2) ? xn[base + (size_t)(s0-2)*1024] : 0.f;
  float xw2 = (s0>=1) ? xn[base + (size_t)(s0-1)*1024] : 0.f;

  float h = 0.f, pa = 1.f;
  #pragma unroll
  for (int s8=0; s8<32; s8++){
    int s = s0 + s8;
    float xw3 = xn[base + (size_t)s*1024];
    float uv = silu_f(xw0*cw0 + xw1*cw1 + xw2*cw2 + xw3*cw3);
    xw0=xw1; xw1=xw2; xw2=xw3;
    float dtv = dt[base + (size_t)s*1024];
    float Bpv = pp[s*96 + 64 + n];
    float a  = expf(dtv*A);
    float bt = tiny ? dtv : (a-1.f)*invA;
    At[s8] = a;
    float ip = bt*Bpv*uv;
    inp[s8] = ip;
    h = a*h + ip;
    pa *= a;
  }
  sA[tid]=pa; sB[tid]=h;
  __syncthreads();
  if (tid < 16){
    float H = 0.f;
    #pragma unroll
    for (int c2=0;c2<16;c2++){
      sH[c2*16+tid] = H;
      H = sA[c2*16+tid]*H + sB[c2*16+tid];
    }
  }
  __syncthreads();

  h = sH[tid];
  // phase C: rescan; conv recomputed (xn now L1/L2-hot) for the epilogue u term
  xw0 = (s0>=3) ? xn[base + (size_t)(s0-3)*1024] : 0.f;
  xw1 = (s0>=2) ? xn[base + (size_t)(s0-2)*1024] : 0.f;
  xw2 = (s0>=1) ? xn[base + (size_t)(s0-1)*1024] : 0.f;
  #pragma unroll
  for (int s8=0; s8<32; s8++){
    int s = s0 + s8;
    float xw3 = xn[base + (size_t)s*1024];
    float uv = silu_f(xw0*cw0 + xw1*cw1 + xw2*cw2 + xw3*cw3);
    xw0=xw1; xw1=xw2; xw2=xw3;
    h = At[s8]*h + inp[s8];
    float Cpv = pp[s*96 + 80 + n];
    float cc = Cpv*h;
    cc += __shfl_xor(cc,1);
    cc += __shfl_xor(cc,2);
    cc += __shfl_xor(cc,4);
    cc += __shfl_xor(cc,8);
    if (n==0){
      float zv = z[base + (size_t)s*1024];
      y2b[base + (size_t)s*1024] = f2b((cc + uv*dscale) * (zv/(1.f+expf(-zv))));
    }
  }
}

// ---------------- bf16 MFMA GEMM, global_load_lds both operands ----------------
template<int TN, int EPI, bool OBF>
__global__ __launch_bounds__(256) void k_bgemm(
    const ushort* __restrict__ A,
    const ushort* __restrict__ W,
    const float* __restrict__ bias,
    const float* __restrict__ resid,
    void* __restrict__ Cout,
    int ldc, int nmax, int K)
{
  constexpr int WN = (TN==128)?2:1;
  constexpr int WM = 4/WN;
  constexpr int MR = 128/(WM*16);   // 4 (TN=128) or 2 (TN=64)
  constexpr int NR = TN/(WN*16);    // 4

  __shared__ ushort As[128*64] __attribute__((aligned(16)));
  __shared__ ushort Bs[TN*64]  __attribute__((aligned(16)));
  const int t = threadIdx.x;
  const int w = t >> 6, lane = t & 63;
  const int wn = w % WN, wm = w / WN;
  const int m0 = blockIdx.y * 128;
  const int n0 = blockIdx.x * TN;

  f32x4 acc[MR][NR];
  #pragma unroll
  for (int i=0;i<MR;i++)
    #pragma unroll
    for (int j=0;j<NR;j++) acc[i][j] = (f32x4){0.f,0.f,0.f,0.f};

  const int srow = (lane >> 3);
  const int scol = (lane & 7) * 8;

  for (int k0 = 0; k0 < K; k0 += 64){
    __syncthreads();
    #pragma unroll
    for (int i=0;i<4;i++){
      int chunk = i*4 + w;
      int row = chunk*8 + srow;
      gl_lds16(A + (size_t)(m0 + row)*K + k0 + scol, &As[chunk*512]);
    }
    #pragma unroll
    for (int i=0;i<TN/32;i++){
      int chunk = i*4 + w;
      int row = chunk*8 + srow;
      gl_lds16(W + (size_t)(n0 + row)*K + k0 + scol, &Bs[chunk*512]);
    }
    __syncthreads();
    #pragma unroll
    for (int kk=0; kk<2; ++kk){
      bf16x8 a[MR], b[NR];
      const int cofs = kk*32 + (lane>>4)*8;
      const int fr = lane & 15;
      #pragma unroll
      for (int am=0; am<MR; am++)
        a[am] = *(const bf16x8*)&As[(wm*(MR*16) + am*16 + fr)*64 + cofs];
      #pragma unroll
      for (int bn=0; bn<NR; bn++)
        b[bn] = *(const bf16x8*)&Bs[(wn*(NR*16) + bn*16 + fr)*64 + cofs];
      #pragma unroll
      for (int am=0; am<MR; am++)
        #pragma unroll
        for (int bn=0; bn<NR; bn++)
          acc[am][bn] = __builtin_amdgcn_mfma_f32_16x16x32_bf16(a[am], b[bn], acc[am][bn], 0, 0, 0);
    }
  }

  #pragma unroll
  for (int am=0; am<MR; am++){
    #pragma unroll
    for (int bn=0; bn<NR; bn++){
      int r0 = m0 + wm*(MR*16) + am*16 + ((lane>>4)<<2);
      int c  = n0 + wn*(NR*16) + bn*16 + (lane&15);
      if (c >= nmax) continue;
      float bv = 0.f;
      if constexpr (EPI==1 || EPI==2 || EPI==3 || EPI==5) bv = bias[c];
      #pragma unroll
      for (int r=0; r<4; r++){
        float v = acc[am][bn][r];
        if constexpr (EPI==1 || EPI==2 || EPI==3 || EPI==5) v += bv;
        if constexpr (EPI==2) v = gelu_f(v);
        if constexpr (EPI==3) v = softplus_f(v);
        if constexpr (EPI==4 || EPI==5) v += resid[(size_t)(r0+r)*ldc + c];
        if constexpr (OBF)
          ((ushort*)Cout)[(size_t)(r0+r)*ldc + c] = f2b(v);
        else
          ((float*)Cout)[(size_t)(r0+r)*ldc + c] = v;
      }
    }
  }
}

extern "C" void kernel_launch(void* const* d_in, const int* in_sizes, int n_in,
                              void* d_out, int out_size, void* d_ws, size_t ws_size,
                              hipStream_t stream)
{
  const int*   ids    = (const int*)d_in[0];
  const int*   tsteps = (const int*)d_in[1];
  const float* tok    = (const float*)d_in[2];
  const float* tw1    = (const float*)d_in[3];
  const float* tb1    = (const float*)d_in[4];
  const float* tw2    = (const float*)d_in[5];
  const float* tb2    = (const float*)d_in[6];
  const float* n1s    = (const float*)d_in[7];
  const float* n1b    = (const float*)d_in[8];
  // d_in[9] = xW, unused by the reference
  const float* zW     = (const float*)d_in[10];
  const float* pW     = (const float*)d_in[11];
  const float* cW     = (const float*)d_in[12];
  const float* dtW    = (const float*)d_in[13];
  const float* dtb    = (const float*)d_in[14];
  const float* alog   = (const float*)d_in[15];
  const float* Dp     = (const float*)d_in[16];
  const float* oW     = (const float*)d_in[17];
  const float* n2s    = (const float*)d_in[18];
  const float* n2b    = (const float*)d_in[19];
  const float* m1W    = (const float*)d_in[20];
  const float* m1b    = (const float*)d_in[21];
  const float* m2W    = (const float*)d_in[22];
  const float* m2b    = (const float*)d_in[23];
  const float* nos    = (const float*)d_in[24];
  const float* nob    = (const float*)d_in[25];
  const float* hW     = (const float*)d_in[26];
  const float* hb     = (const float*)d_in[27];

  float* ws = (float*)d_ws;
  const size_t F = 1u<<20;
  float*  x    = ws;                    // 1M floats
  float*  xn   = ws + 1*F;
  float*  z    = ws + 2*F;
  float*  dt   = ws + 3*F;
  float*  p    = ws + 4*F;              // 1024x96
  float*  t0   = ws + 4*F + 100000;
  float*  t1   = t0 + 2048;
  float*  t2   = t1 + 8192;
  ushort* pb64 = (ushort*)(ws + 4*F + 114688);   // 1024x64 bf16
  ushort* xnb  = (ushort*)(ws + 5*F);            // 1M ushorts
  ushort* y2b  = (ushort*)(ws + 5*F + 524288);
  ushort* h1b  = (ushort*)(ws + 6*F);            // 4M ushorts
  ushort* wdtb = (ushort*)(ws + 8*F);            // 1024x64
  ushort* wpb  = (ushort*)(ws + 8*F + 32768);    // 128x1024 (padded)
  ushort* wzb  = (ushort*)(ws + 9*F);            // 1024x1024
  ushort* wob  = (ushort*)(ws + 9*F + 524288);
  ushort* wm1b = (ushort*)(ws + 10*F);           // 4096x1024
  ushort* wm2b = (ushort*)(ws + 12*F);           // 1024x4096
  ushort* whb  = (ushort*)(ws + 9*F);            // head half (reuses wzb..wm2b)

  dim3 blk(256);
  k_temb0<<<dim3(4),    blk, 0, stream>>>(tsteps, t0);
  k_temb1<<<dim3(2048), blk, 0, stream>>>(t0, tw1, tb1, t1);
  k_temb2<<<dim3(512),  blk, 0, stream>>>(t1, tw2, tb2, t2);
  k_embed<<<dim3(4096), blk, 0, stream>>>(ids, tok, t2, x);

  for (int l=0; l<4; l++){
    // all weight cvts for this layer in one BW-bound dispatch
    k_cvtall<<<dim3(10432), blk, 0, stream>>>(
        zW + (size_t)l*1024*1024, pW + (size_t)l*96*1024,
        dtW + (size_t)l*1024*64,  oW + (size_t)l*1024*1024,
        m1W + (size_t)l*4096*1024, m2W + (size_t)l*1024*4096,
        wzb, wpb, wdtb, wob, wm1b, wm2b);
    k_ln<<<dim3(1024), blk, 0, stream>>>(x, n1s + l*1024, n1b + l*1024, xn, xnb);
    // z = xn @ zW^T
    k_bgemm<64,0,false><<<dim3(16,8), blk, 0, stream>>>(xnb, wzb, nullptr, nullptr, z, 1024, 1024, 1024);
    // p = xn @ pW^T
    k_bgemm<64,0,false><<<dim3(2,8), blk, 0, stream>>>(xnb, wpb, nullptr, nullptr, p, 96, 96, 1024);
    // dt = softplus(p[:,:64] @ dtW^T + dtb)
    k_cvtp<<<dim3(64), blk, 0, stream>>>(p, pb64);
    k_bgemm<64,3,false><<<dim3(16,8), blk, 0, stream>>>(pb64, wdtb, dtb + l*1024, nullptr, dt, 1024, 1024, 64);
    // fused conv + scan + (y+u*Dp)*silu(z) -> y2b
    k_scanf<<<dim3(2048), blk, 0, stream>>>(dt, xn, p, alog + l*1024*16, z, Dp + l*1024, cW + l*1024*4, y2b);
    // x += y2 @ oW^T
    k_bgemm<64,4,false><<<dim3(16,8), blk, 0, stream>>>(y2b, wob, nullptr, x, x, 1024, 1024, 1024);
    // MLP
    k_ln<<<dim3(1024), blk, 0, stream>>>(x, n2s + l*1024, n2b + l*1024, xn, xnb);
    k_bgemm<128,2,true><<<dim3(32,8), blk, 0, stream>>>(xnb, wm1b, m1b + l*4096, nullptr, h1b, 4096, 4096, 1024);
    k_bgemm<64,5,false><<<dim3(16,8), blk, 0, stream>>>(h1b, wm2b, m2b + l*1024, x, x, 1024, 1024, 4096);
  }
  k_ln<<<dim3(1024), blk, 0, stream>>>(x, nos, nob, xn, xnb);
  // head in two halves; x=n fast => W half streamed once, L3 serves m re-sweeps
  for (int h=0; h<2; h++){
    k_cvt<<<dim3(16000), blk, 0, stream>>>(hW + (size_t)h*16000*1024, whb, 4096000);
    k_bgemm<128,1,false><<<dim3(125,8), blk, 0, stream>>>(xnb, whb, hb + h*16000, nullptr,
                                                          (float*)d_out + h*16000, 32000, 32000, 1024);
  }
}

// Round 8
// 1169.214 us; speedup vs baseline: 1.4189x; 1.4189x over previous
//
#include <hip/hip_runtime.h>
#include <math.h>

// HydraScaleLM forward. Round 8: scanf v3 — LDS-staged dt/xn/z columns,
// 512 threads (32 chunks x 16 n, 16-step chunks), At/inp[16] regs (~70 VGPR),
// XCD swizzle kept. Everything else = round 7 (cvtall, gl_lds bgemm, temb).
// Shapes: B=2, S=512, D=1024, DEPTH=4, N=16, K=4, R=64, MLP=4096, V=32000. M=1024.

#define DEV __device__ __forceinline__
typedef unsigned int u32;
typedef unsigned short ushort;
typedef __bf16 bf16x8 __attribute__((ext_vector_type(8)));
typedef float f32x4 __attribute__((ext_vector_type(4)));
typedef ushort us8 __attribute__((ext_vector_type(8)));

DEV float silu_f(float x){ return x / (1.f + expf(-x)); }
DEV float gelu_f(float x){ return 0.5f * x * (1.f + erff(x * 0.70710678118654752f)); }
DEV float softplus_f(float x){ return (x > 20.f) ? x : log1pf(expf(x)); }
DEV ushort f2b(float f){
  u32 u = __builtin_bit_cast(u32, f);
  return (ushort)((u + 0x7fffu + ((u >> 16) & 1u)) >> 16);
}

DEV void gl_lds16(const ushort* g, ushort* l){
  __builtin_amdgcn_global_load_lds(
      (const __attribute__((address_space(1))) u32*)g,
      (__attribute__((address_space(3))) u32*)l, 16, 0, 0);
}

// ---------------- fused per-layer weight conversion ----------------
__global__ __launch_bounds__(256) void k_cvtall(
    const float* __restrict__ zWl, const float* __restrict__ pWl,
    const float* __restrict__ dtWl, const float* __restrict__ oWl,
    const float* __restrict__ m1Wl, const float* __restrict__ m2Wl,
    ushort* __restrict__ wzb, ushort* __restrict__ wpb,
    ushort* __restrict__ wdtb, ushort* __restrict__ wob,
    ushort* __restrict__ wm1b, ushort* __restrict__ wm2b)
{
  int i = blockIdx.x*256 + threadIdx.x;
  const float* src; ushort* dst; int j;
  if (i < 262144){ src = zWl; dst = wzb; j = i; }
  else if (i < 262144+32768){
    j = i - 262144; dst = wpb;
    int row = j >> 8;
    if (row >= 96){ ushort4 o0={0,0,0,0}; ((ushort4*)dst)[j] = o0; return; }
    src = pWl;
  }
  else if (i < 262144+32768+16384){ j = i - (262144+32768); src = dtWl; dst = wdtb; }
  else if (i < 573440)            { j = i - (262144+32768+16384); src = oWl; dst = wob; }
  else if (i < 573440+1048576)    { j = i - 573440; src = m1Wl; dst = wm1b; }
  else if (i < 2670656)           { j = i - (573440+1048576); src = m2Wl; dst = wm2b; }
  else return;
  float4 v = ((const float4*)src)[j];
  ushort4 o; o.x=f2b(v.x); o.y=f2b(v.y); o.z=f2b(v.z); o.w=f2b(v.w);
  ((ushort4*)dst)[j] = o;
}

__global__ __launch_bounds__(256) void k_cvt(const float* __restrict__ in, ushort* __restrict__ out, int n4){
  int i = blockIdx.x*256 + threadIdx.x;
  if (i >= n4) return;
  float4 v = ((const float4*)in)[i];
  ushort4 o; o.x=f2b(v.x); o.y=f2b(v.y); o.z=f2b(v.z); o.w=f2b(v.w);
  ((ushort4*)out)[i] = o;
}

// p[1024][96] fp32 -> pb[1024][64] bf16 (dt_un slice)
__global__ __launch_bounds__(256) void k_cvtp(const float* __restrict__ p, ushort* __restrict__ pb){
  int i = blockIdx.x*256 + threadIdx.x;      // 16384 float4s
  int row = i >> 4, c4 = i & 15;
  float4 v = *(const float4*)(p + row*96 + c4*4);
  ushort4 o; o.x=f2b(v.x); o.y=f2b(v.y); o.z=f2b(v.z); o.w=f2b(v.w);
  *(ushort4*)(pb + row*64 + c4*4) = o;
}

// ---------------- time embedding ----------------
__global__ __launch_bounds__(256) void k_temb0(const int* __restrict__ ts, float* __restrict__ temb0){
  int t = blockIdx.x*256 + threadIdx.x;
  if (t >= 2*512) return;
  int b = t >> 9, i = t & 511;
  float tv = (float)ts[b];
  float inv = expf(-(9.210340371976184f/512.f) * (float)i);
  float a = tv * inv;
  temb0[b*1024 + i]       = sinf(a);
  temb0[b*1024 + 512 + i] = cosf(a);
}

__global__ __launch_bounds__(256) void k_temb1(const float* __restrict__ t0, const float* __restrict__ w1,
                                               const float* __restrict__ b1, float* __restrict__ t1){
  int o = blockIdx.x*4 + (threadIdx.x >> 6);
  int lane = threadIdx.x & 63;
  int b = o >> 12, j = o & 4095;
  const float4* xr = (const float4*)(t0 + b*1024);
  const float4* wr = (const float4*)(w1 + (size_t)j*1024);
  float acc = 0.f;
  #pragma unroll
  for (int i=0;i<4;i++){
    float4 x4 = xr[i*64 + lane], w4 = wr[i*64 + lane];
    acc += x4.x*w4.x + x4.y*w4.y + x4.z*w4.z + x4.w*w4.w;
  }
  #pragma unroll
  for (int off=32; off; off>>=1) acc += __shfl_down(acc, off);
  if (lane==0) t1[o] = silu_f(acc + b1[j]);
}

__global__ __launch_bounds__(256) void k_temb2(const float* __restrict__ t1, const float* __restrict__ w2,
                                               const float* __restrict__ b2, float* __restrict__ t2){
  int o = blockIdx.x*4 + (threadIdx.x >> 6);
  int lane = threadIdx.x & 63;
  int b = o >> 10, j = o & 1023;
  const float4* xr = (const float4*)(t1 + b*4096);
  const float4* wr = (const float4*)(w2 + (size_t)j*4096);
  float acc = 0.f;
  #pragma unroll
  for (int i=0;i<16;i++){
    float4 x4 = xr[i*64 + lane], w4 = wr[i*64 + lane];
    acc += x4.x*w4.x + x4.y*w4.y + x4.z*w4.z + x4.w*w4.w;
  }
  #pragma unroll
  for (int off=32; off; off>>=1) acc += __shfl_down(acc, off);
  if (lane==0) t2[o] = acc + b2[j];
}

// ---------------- embed ----------------
__global__ __launch_bounds__(256) void k_embed(const int* __restrict__ ids, const float* __restrict__ tok,
                                               const float* __restrict__ t2, float* __restrict__ x){
  int i = blockIdx.x*256 + threadIdx.x;
  int bs = i >> 10, d = i & 1023;
  int id = ids[bs];
  x[i] = tok[(size_t)id*1024 + d] + t2[((bs >> 9) << 10) + d];
}

// ---------------- layernorm: writes fp32 + bf16 ----------------
__global__ __launch_bounds__(256) void k_ln(const float* __restrict__ x, const float* __restrict__ sc,
                                            const float* __restrict__ bi, float* __restrict__ o,
                                            ushort* __restrict__ obf){
  int row = blockIdx.x;
  int t = threadIdx.x;
  float4 v = ((const float4*)(x + (size_t)row*1024))[t];
  float sum = v.x+v.y+v.z+v.w;
  float sq  = v.x*v.x+v.y*v.y+v.z*v.z+v.w*v.w;
  for (int o_=32;o_;o_>>=1){ sum += __shfl_down(sum,o_); sq += __shfl_down(sq,o_); }
  __shared__ float ps[8];
  int lane = t & 63, wid = t >> 6;
  if (lane==0){ ps[wid]=sum; ps[4+wid]=sq; }
  __syncthreads();
  float tot = ps[0]+ps[1]+ps[2]+ps[3];
  float tsq = ps[4]+ps[5]+ps[6]+ps[7];
  float m = tot * (1.f/1024.f);
  float var = tsq*(1.f/1024.f) - m*m;
  float r = rsqrtf(var + 1e-5f);
  float4 s4 = ((const float4*)sc)[t];
  float4 b4 = ((const float4*)bi)[t];
  float4 o4;
  o4.x = (v.x-m)*r*s4.x + b4.x;
  o4.y = (v.y-m)*r*s4.y + b4.y;
  o4.z = (v.z-m)*r*s4.z + b4.z;
  o4.w = (v.w-m)*r*s4.w + b4.w;
  ((float4*)(o + (size_t)row*1024))[t] = o4;
  ushort4 ob; ob.x=f2b(o4.x); ob.y=f2b(o4.y); ob.z=f2b(o4.z); ob.w=f2b(o4.w);
  ((ushort4*)(obf + (size_t)row*1024))[t] = ob;
}

// ---------------- fused conv + chunk-parallel SSM scan + ypost (v3) ----------------
// 512 threads = 32 chunks x 16 n; 16-step chunks. dt/xn/z columns staged in LDS
// (one coalesced burst); phase A/C read LDS. XCD swizzle keeps adjacent-d blocks
// on one L2. uv for the epilogue recomputed from LDS in the n==0 lane only.
__global__ __launch_bounds__(512) void k_scanf(
    const float* __restrict__ dt, const float* __restrict__ xn,
    const float* __restrict__ p,  const float* __restrict__ alog,
    const float* __restrict__ z,  const float* __restrict__ Dp,
    const float* __restrict__ cw, ushort* __restrict__ y2b)
{
  const int bid = blockIdx.x;                      // 2048
  const int logical = (bid & 7)*256 + (bid >> 3);  // XCD k owns logical k*256..+255
  const int d = logical & 1023;
  const int b = logical >> 10;
  const int tid = threadIdx.x;
  const int c = tid >> 4, n = tid & 15;            // c: 0..31
  const float al = alog[d*16 + n];
  const float A = -expf(al);
  const float invA = 1.f/(A + 1e-10f);
  const bool tiny = fabsf(A) < 1e-8f;
  const float dscale = Dp[d];
  const float cw0 = cw[d*4], cw1 = cw[d*4+1], cw2 = cw[d*4+2], cw3 = cw[d*4+3];
  const size_t base = (size_t)b*512*1024 + d;
  const float* pp = p + (size_t)b*512*96;
  const int s0 = c*16;

  __shared__ float sXN[520];   // sXN[i] = xn(s=i-3), i=0..514
  __shared__ float sDT[512], sZ[512];
  __shared__ float sA[512], sB[512], sH[512];

  // stage columns (independent loads, one drain)
  {
    int s = tid - 3;
    sXN[tid] = (s >= 0) ? xn[base + (size_t)s*1024] : 0.f;
    if (tid < 3) sXN[512 + tid] = xn[base + (size_t)(509 + tid)*1024];
    sDT[tid] = dt[base + (size_t)tid*1024];
    sZ[tid]  = z [base + (size_t)tid*1024];
  }
  __syncthreads();

  // phase A: per-chunk (prod At, h_end) from h=0
  float At[16], inp[16];
  float h = 0.f, pa = 1.f;
  #pragma unroll
  for (int s8=0; s8<16; s8++){
    int s = s0 + s8;
    float uv = silu_f(sXN[s]*cw0 + sXN[s+1]*cw1 + sXN[s+2]*cw2 + sXN[s+3]*cw3);
    float dtv = sDT[s];
    float Bpv = pp[s*96 + 64 + n];
    float a  = expf(dtv*A);
    float bt = tiny ? dtv : (a-1.f)*invA;
    At[s8] = a;
    float ip = bt*Bpv*uv;
    inp[s8] = ip;
    h = a*h + ip;
    pa *= a;
  }
  sA[tid]=pa; sB[tid]=h;
  __syncthreads();
  if (tid < 16){
    float H = 0.f;
    #pragma unroll
    for (int c2=0;c2<32;c2++){
      sH[c2*16+tid] = H;
      H = sA[c2*16+tid]*H + sB[c2*16+tid];
    }
  }
  __syncthreads();

  // phase C: rescan with true h0
  h = sH[tid];
  #pragma unroll
  for (int s8=0; s8<16; s8++){
    int s = s0 + s8;
    h = At[s8]*h + inp[s8];
    float Cpv = pp[s*96 + 80 + n];
    float cc = Cpv*h;
    cc += __shfl_xor(cc,1);
    cc += __shfl_xor(cc,2);
    cc += __shfl_xor(cc,4);
    cc += __shfl_xor(cc,8);
    if (n==0){
      float uv = silu_f(sXN[s]*cw0 + sXN[s+1]*cw1 + sXN[s+2]*cw2 + sXN[s+3]*cw3);
      float zv = sZ[s];
      y2b[base + (size_t)s*1024] = f2b((cc + uv*dscale) * (zv/(1.f+expf(-zv))));
    }
  }
}

// ---------------- bf16 MFMA GEMM, global_load_lds both operands ----------------
template<int TN, int EPI, bool OBF>
__global__ __launch_bounds__(256) void k_bgemm(
    const ushort* __restrict__ A,
    const ushort* __restrict__ W,
    const float* __restrict__ bias,
    const float* __restrict__ resid,
    void* __restrict__ Cout,
    int ldc, int nmax, int K)
{
  constexpr int WN = (TN==128)?2:1;
  constexpr int WM = 4/WN;
  constexpr int MR = 128/(WM*16);   // 4 (TN=128) or 2 (TN=64)
  constexpr int NR = TN/(WN*16);    // 4

  __shared__ ushort As[128*64] __attribute__((aligned(16)));
  __shared__ ushort Bs[TN*64]  __attribute__((aligned(16)));
  const int t = threadIdx.x;
  const int w = t >> 6, lane = t & 63;
  const int wn = w % WN, wm = w / WN;
  const int m0 = blockIdx.y * 128;
  const int n0 = blockIdx.x * TN;

  f32x4 acc[MR][NR];
  #pragma unroll
  for (int i=0;i<MR;i++)
    #pragma unroll
    for (int j=0;j<NR;j++) acc[i][j] = (f32x4){0.f,0.f,0.f,0.f};

  const int srow = (lane >> 3);
  const int scol = (lane & 7) * 8;

  for (int k0 = 0; k0 < K; k0 += 64){
    __syncthreads();
    #pragma unroll
    for (int i=0;i<4;i++){
      int chunk = i*4 + w;
      int row = chunk*8 + srow;
      gl_lds16(A + (size_t)(m0 + row)*K + k0 + scol, &As[chunk*512]);
    }
    #pragma unroll
    for (int i=0;i<TN/32;i++){
      int chunk = i*4 + w;
      int row = chunk*8 + srow;
      gl_lds16(W + (size_t)(n0 + row)*K + k0 + scol, &Bs[chunk*512]);
    }
    __syncthreads();
    #pragma unroll
    for (int kk=0; kk<2; ++kk){
      bf16x8 a[MR], b[NR];
      const int cofs = kk*32 + (lane>>4)*8;
      const int fr = lane & 15;
      #pragma unroll
      for (int am=0; am<MR; am++)
        a[am] = *(const bf16x8*)&As[(wm*(MR*16) + am*16 + fr)*64 + cofs];
      #pragma unroll
      for (int bn=0; bn<NR; bn++)
        b[bn] = *(const bf16x8*)&Bs[(wn*(NR*16) + bn*16 + fr)*64 + cofs];
      #pragma unroll
      for (int am=0; am<MR; am++)
        #pragma unroll
        for (int bn=0; bn<NR; bn++)
          acc[am][bn] = __builtin_amdgcn_mfma_f32_16x16x32_bf16(a[am], b[bn], acc[am][bn], 0, 0, 0);
    }
  }

  #pragma unroll
  for (int am=0; am<MR; am++){
    #pragma unroll
    for (int bn=0; bn<NR; bn++){
      int r0 = m0 + wm*(MR*16) + am*16 + ((lane>>4)<<2);
      int c  = n0 + wn*(NR*16) + bn*16 + (lane&15);
      if (c >= nmax) continue;
      float bv = 0.f;
      if constexpr (EPI==1 || EPI==2 || EPI==3 || EPI==5) bv = bias[c];
      #pragma unroll
      for (int r=0; r<4; r++){
        float v = acc[am][bn][r];
        if constexpr (EPI==1 || EPI==2 || EPI==3 || EPI==5) v += bv;
        if constexpr (EPI==2) v = gelu_f(v);
        if constexpr (EPI==3) v = softplus_f(v);
        if constexpr (EPI==4 || EPI==5) v += resid[(size_t)(r0+r)*ldc + c];
        if constexpr (OBF)
          ((ushort*)Cout)[(size_t)(r0+r)*ldc + c] = f2b(v);
        else
          ((float*)Cout)[(size_t)(r0+r)*ldc + c] = v;
      }
    }
  }
}

extern "C" void kernel_launch(void* const* d_in, const int* in_sizes, int n_in,
                              void* d_out, int out_size, void* d_ws, size_t ws_size,
                              hipStream_t stream)
{
  const int*   ids    = (const int*)d_in[0];
  const int*   tsteps = (const int*)d_in[1];
  const float* tok    = (const float*)d_in[2];
  const float* tw1    = (const float*)d_in[3];
  const float* tb1    = (const float*)d_in[4];
  const float* tw2    = (const float*)d_in[5];
  const float* tb2    = (const float*)d_in[6];
  const float* n1s    = (const float*)d_in[7];
  const float* n1b    = (const float*)d_in[8];
  // d_in[9] = xW, unused by the reference
  const float* zW     = (const float*)d_in[10];
  const float* pW     = (const float*)d_in[11];
  const float* cW     = (const float*)d_in[12];
  const float* dtW    = (const float*)d_in[13];
  const float* dtb    = (const float*)d_in[14];
  const float* alog   = (const float*)d_in[15];
  const float* Dp     = (const float*)d_in[16];
  const float* oW     = (const float*)d_in[17];
  const float* n2s    = (const float*)d_in[18];
  const float* n2b    = (const float*)d_in[19];
  const float* m1W    = (const float*)d_in[20];
  const float* m1b    = (const float*)d_in[21];
  const float* m2W    = (const float*)d_in[22];
  const float* m2b    = (const float*)d_in[23];
  const float* nos    = (const float*)d_in[24];
  const float* nob    = (const float*)d_in[25];
  const float* hW     = (const float*)d_in[26];
  const float* hb     = (const float*)d_in[27];

  float* ws = (float*)d_ws;
  const size_t F = 1u<<20;
  float*  x    = ws;                    // 1M floats
  float*  xn   = ws + 1*F;
  float*  z    = ws + 2*F;
  float*  dt   = ws + 3*F;
  float*  p    = ws + 4*F;              // 1024x96
  float*  t0   = ws + 4*F + 100000;
  float*  t1   = t0 + 2048;
  float*  t2   = t1 + 8192;
  ushort* pb64 = (ushort*)(ws + 4*F + 114688);   // 1024x64 bf16
  ushort* xnb  = (ushort*)(ws + 5*F);            // 1M ushorts
  ushort* y2b  = (ushort*)(ws + 5*F + 524288);
  ushort* h1b  = (ushort*)(ws + 6*F);            // 4M ushorts
  ushort* wdtb = (ushort*)(ws + 8*F);            // 1024x64
  ushort* wpb  = (ushort*)(ws + 8*F + 32768);    // 128x1024 (padded)
  ushort* wzb  = (ushort*)(ws + 9*F);            // 1024x1024
  ushort* wob  = (ushort*)(ws + 9*F + 524288);
  ushort* wm1b = (ushort*)(ws + 10*F);           // 4096x1024
  ushort* wm2b = (ushort*)(ws + 12*F);           // 1024x4096
  ushort* whb  = (ushort*)(ws + 9*F);            // head half (reuses wzb..wm2b)

  dim3 blk(256);
  k_temb0<<<dim3(4),    blk, 0, stream>>>(tsteps, t0);
  k_temb1<<<dim3(2048), blk, 0, stream>>>(t0, tw1, tb1, t1);
  k_temb2<<<dim3(512),  blk, 0, stream>>>(t1, tw2, tb2, t2);
  k_embed<<<dim3(4096), blk, 0, stream>>>(ids, tok, t2, x);

  for (int l=0; l<4; l++){
    k_cvtall<<<dim3(10432), blk, 0, stream>>>(
        zW + (size_t)l*1024*1024, pW + (size_t)l*96*1024,
        dtW + (size_t)l*1024*64,  oW + (size_t)l*1024*1024,
        m1W + (size_t)l*4096*1024, m2W + (size_t)l*1024*4096,
        wzb, wpb, wdtb, wob, wm1b, wm2b);
    k_ln<<<dim3(1024), blk, 0, stream>>>(x, n1s + l*1024, n1b + l*1024, xn, xnb);
    // z = xn @ zW^T
    k_bgemm<64,0,false><<<dim3(16,8), blk, 0, stream>>>(xnb, wzb, nullptr, nullptr, z, 1024, 1024, 1024);
    // p = xn @ pW^T
    k_bgemm<64,0,false><<<dim3(2,8), blk, 0, stream>>>(xnb, wpb, nullptr, nullptr, p, 96, 96, 1024);
    // dt = softplus(p[:,:64] @ dtW^T + dtb)
    k_cvtp<<<dim3(64), blk, 0, stream>>>(p, pb64);
    k_bgemm<64,3,false><<<dim3(16,8), blk, 0, stream>>>(pb64, wdtb, dtb + l*1024, nullptr, dt, 1024, 1024, 64);
    // fused conv + scan + (y+u*Dp)*silu(z) -> y2b
    k_scanf<<<dim3(2048), dim3(512), 0, stream>>>(dt, xn, p, alog + l*1024*16, z, Dp + l*1024, cW + l*1024*4, y2b);
    // x += y2 @ oW^T
    k_bgemm<64,4,false><<<dim3(16,8), blk, 0, stream>>>(y2b, wob, nullptr, x, x, 1024, 1024, 1024);
    // MLP
    k_ln<<<dim3(1024), blk, 0, stream>>>(x, n2s + l*1024, n2b + l*1024, xn, xnb);
    k_bgemm<128,2,true><<<dim3(32,8), blk, 0, stream>>>(xnb, wm1b, m1b + l*4096, nullptr, h1b, 4096, 4096, 1024);
    k_bgemm<64,5,false><<<dim3(16,8), blk, 0, stream>>>(h1b, wm2b, m2b + l*1024, x, x, 1024, 1024, 4096);
  }
  k_ln<<<dim3(1024), blk, 0, stream>>>(x, nos, nob, xn, xnb);
  // head in two halves; x=n fast => W half streamed once, L3 serves m re-sweeps
  for (int h=0; h<2; h++){
    k_cvt<<<dim3(16000), blk, 0, stream>>>(hW + (size_t)h*16000*1024, whb, 4096000);
    k_bgemm<128,1,false><<<dim3(125,8), blk, 0, stream>>>(xnb, whb, hb + h*16000, nullptr,
                                                          (float*)d_out + h*16000, 32000, 32000, 1024);
  }
}